// Round 1
// baseline (147.089 us; speedup 1.0000x reference)
//
#include <hip/hip_runtime.h>

// Additive (Bahdanau) attention, fp32.
// B=2, L=512, S=512, H=8, E=32, D=64.
// scores[b,h,l,s] = sum_e tanh(q[b,l,h,e] + k[b,s,h,e]) * v[e]  (+ masks)
// A = softmax_s(scores); out[b,l,h,d] = sum_s A * values[b,s,h,d]

#define BB 2
#define LL 512
#define SS 512
#define HH 8
#define EE 32
#define DD 64
#define TS 128   // s-tile staged in LDS

__global__ __launch_bounds__(256) void addattn_kernel(
    const float* __restrict__ q,      // (B,L,H,E)
    const float* __restrict__ k,      // (B,S,H,E)
    const float* __restrict__ vals,   // (B,S,H,D)
    const float* __restrict__ vvec,   // (E)
    const float* __restrict__ mask,   // (L,S)
    const float* __restrict__ klen,   // (B,S)
    float* __restrict__ out)          // (B,L,H,D)
{
    // keys tile, scaled by 2, float4 over e, XOR-swizzled on ss to keep
    // the read pattern (fixed e4, lanes = different ss) conflict-free.
    __shared__ float4 sk[EE / 4][TS];
    __shared__ __align__(16) float sA[4][SS];

    const int tid  = threadIdx.x;
    const int w    = tid >> 6;        // wave id 0..3
    const int lane = tid & 63;
    const int bh   = blockIdx.x >> 7; // 16 (b,h) pairs, 128 l-blocks each
    const int lblk = blockIdx.x & 127;
    const int b    = bh >> 3;
    const int h    = bh & 7;
    const int l    = lblk * 4 + w;    // this wave's output row

    // q row scaled by 2 (for tanh(x) = 1 - 2*rcp(exp(2x)+1)), in registers.
    // Wave-uniform (all lanes same values) — global loads broadcast.
    float4 qs[EE / 4];
    const float4* qrow = (const float4*)(q + (((size_t)b * LL + l) * HH + h) * EE);
    #pragma unroll
    for (int i = 0; i < EE / 4; i++) {
        float4 t = qrow[i];
        qs[i] = make_float4(2.f * t.x, 2.f * t.y, 2.f * t.z, 2.f * t.w);
    }
    // v2 = -2*v and vsum = sum(v):  score = vsum + sum_e v2[e]*rcp(exp(2x)+1)
    float4 v2[EE / 4];
    float vsum = 0.f;
    const float4* vr = (const float4*)vvec;
    #pragma unroll
    for (int i = 0; i < EE / 4; i++) {
        float4 t = vr[i];
        vsum += t.x + t.y + t.z + t.w;
        v2[i] = make_float4(-2.f * t.x, -2.f * t.y, -2.f * t.z, -2.f * t.w);
    }

    // ---- Phase 1: scores. Lane owns s = lane + i*64, i = 0..7. ----
    float sc[SS / 64];
    const float4* krow = (const float4*)(k + ((size_t)b * SS * HH + h) * EE);
    for (int t = 0; t < SS / TS; t++) {
        __syncthreads();
        // cooperative tile load: 128 s-rows x 8 float4, 256 threads x 4 iters
        #pragma unroll
        for (int i = 0; i < (TS * (EE / 4)) / 256; i++) {
            int idx = tid + i * 256;
            int ss  = idx >> 3;       // 0..127
            int e4  = idx & 7;        // 0..7  (consecutive threads -> coalesced)
            float4 kv = krow[(size_t)(t * TS + ss) * (HH * EE / 4) + e4];
            kv.x *= 2.f; kv.y *= 2.f; kv.z *= 2.f; kv.w *= 2.f;
            sk[e4][ss ^ e4] = kv;     // swizzled store
        }
        __syncthreads();
        #pragma unroll
        for (int j = 0; j < 2; j++) {
            int ssl = lane + j * 64;  // local s within tile
            float acc = 0.f;
            #pragma unroll
            for (int e4 = 0; e4 < EE / 4; e4++) {
                float4 kv = sk[e4][ssl ^ e4];   // conflict-free ds_read_b128
                float4 qv = qs[e4];
                float4 vv = v2[e4];
                acc += vv.x * __builtin_amdgcn_rcpf(__expf(qv.x + kv.x) + 1.f);
                acc += vv.y * __builtin_amdgcn_rcpf(__expf(qv.y + kv.y) + 1.f);
                acc += vv.z * __builtin_amdgcn_rcpf(__expf(qv.z + kv.z) + 1.f);
                acc += vv.w * __builtin_amdgcn_rcpf(__expf(qv.w + kv.w) + 1.f);
            }
            sc[t * 2 + j] = vsum + acc;
        }
    }

    // ---- Phase 2: masks + per-row softmax (per-wave, no block sync). ----
    const float* mrow = mask + (size_t)l * SS;
    const float* kl   = klen + (size_t)b * SS;
    #pragma unroll
    for (int i = 0; i < SS / 64; i++) {
        int s = lane + i * 64;
        sc[i] += mrow[s] + kl[s];
    }
    float m = sc[0];
    #pragma unroll
    for (int i = 1; i < SS / 64; i++) m = fmaxf(m, sc[i]);
    #pragma unroll
    for (int off = 1; off < 64; off <<= 1) m = fmaxf(m, __shfl_xor(m, off, 64));
    float p[SS / 64];
    float ssum = 0.f;
    #pragma unroll
    for (int i = 0; i < SS / 64; i++) {
        p[i] = __expf(sc[i] - m);
        ssum += p[i];
    }
    #pragma unroll
    for (int off = 1; off < 64; off <<= 1) ssum += __shfl_xor(ssum, off, 64);
    float inv = __builtin_amdgcn_rcpf(ssum);
    #pragma unroll
    for (int i = 0; i < SS / 64; i++) sA[w][lane + i * 64] = p[i] * inv;
    // sA[w] written and read only by wave w -> compiler's lgkmcnt suffices.

    // ---- Phase 3: PV. lane = d (D=64). values loads coalesced 256B. ----
    const float* vbase = vals + ((size_t)b * SS * HH + h) * DD + lane;
    float a0 = 0.f, a1 = 0.f, a2 = 0.f, a3 = 0.f;
    #pragma unroll 2
    for (int s = 0; s < SS; s += 4) {
        float4 a = *(const float4*)&sA[w][s];   // LDS broadcast
        a0 += a.x * vbase[(size_t)(s + 0) * HH * DD];
        a1 += a.y * vbase[(size_t)(s + 1) * HH * DD];
        a2 += a.z * vbase[(size_t)(s + 2) * HH * DD];
        a3 += a.w * vbase[(size_t)(s + 3) * HH * DD];
    }
    out[(((size_t)b * LL + l) * HH + h) * DD + lane] = (a0 + a1) + (a2 + a3);
}

extern "C" void kernel_launch(void* const* d_in, const int* in_sizes, int n_in,
                              void* d_out, int out_size, void* d_ws, size_t ws_size,
                              hipStream_t stream) {
    const float* q    = (const float*)d_in[0];  // (B,L,H,E)
    const float* k    = (const float*)d_in[1];  // (B,S,H,E)
    const float* vals = (const float*)d_in[2];  // (B,S,H,D)
    const float* vvec = (const float*)d_in[3];  // (E)
    const float* mask = (const float*)d_in[4];  // (L,S)
    const float* klen = (const float*)d_in[5];  // (B,S)
    float* outp = (float*)d_out;                // (B,L,H,D)

    // one wave per (b,h,l) row; 4 waves/block share one (b,h)'s key tiles
    dim3 grid(BB * HH * (LL / 4));
    dim3 block(256);
    addattn_kernel<<<grid, block, 0, stream>>>(q, k, vals, vvec, mask, klen, outp);
}

// Round 2
// 119.288 us; speedup vs baseline: 1.2331x; 1.2331x over previous
//
#include <hip/hip_runtime.h>

// Additive (Bahdanau) attention, fp32 in/out.
// B=2, L=512, S=512, H=8, E=32, D=64.
// scores[b,h,l,s] = sum_e tanh(q[b,l,h,e] + k[b,s,h,e]) * v[e]  (+ masks)
// A = softmax_s(scores); out[b,l,h,d] = sum_s A * values[b,s,h,d]
//
// Block = 4 waves = 4 l-rows sharing one (b,h). Phase 1: LDS-staged K tiles,
// tanh via 1 exp2 + 1 rcp (2*log2e folded into staged q/k). Phase 3: PV as a
// (4x512)x(512x64) GEMM via mfma_f32_16x16x32_bf16 — A = bf16 probs in LDS
// (rows 4..15 zero), B = V fragments straight from L2 (read once per block).

#define BB 2
#define LL 512
#define SS 512
#define HH 8
#define EE 32
#define DD 64
#define TS 128   // s-tile staged in LDS for phase 1

typedef __attribute__((ext_vector_type(8))) short bf16x8;
typedef __attribute__((ext_vector_type(4))) float f32x4;

__device__ __forceinline__ short f2bf(float f) {   // fp32 -> bf16, RNE
    unsigned u = __float_as_uint(f);
    u += 0x7FFFu + ((u >> 16) & 1u);
    return (short)(u >> 16);
}

__device__ __forceinline__ float fast_exp2(float x) {
#if __has_builtin(__builtin_amdgcn_exp2f)
    return __builtin_amdgcn_exp2f(x);   // v_exp_f32
#else
    return exp2f(x);
#endif
}

__global__ __launch_bounds__(256) void addattn_kernel(
    const float* __restrict__ q,      // (B,L,H,E)
    const float* __restrict__ k,      // (B,S,H,E)
    const float* __restrict__ vals,   // (B,S,H,D)
    const float* __restrict__ vvec,   // (E)
    const float* __restrict__ mask,   // (L,S)
    const float* __restrict__ klen,   // (B,S)
    float* __restrict__ out)          // (B,L,H,D)
{
    // keys tile, scaled by 2*log2e, float4 over e, XOR-swizzled on s so the
    // phase-1 read (fixed e4, lanes = different s) is conflict-free.
    __shared__ float4 sk[EE / 4][TS];
    // bf16 softmax probs; row stride 520 shorts = 1040 B -> rows land on
    // different banks AND keep 16B alignment for bf16x8 frag reads.
    __shared__ short sAb[4][SS + 8];

    const int tid  = threadIdx.x;
    const int w    = tid >> 6;        // wave id 0..3 == A row / d-chunk
    const int lane = tid & 63;
    const int bh   = blockIdx.x >> 7; // 16 (b,h) pairs, 128 l-blocks each
    const int lblk = blockIdx.x & 127;
    const int b    = bh >> 3;
    const int h    = bh & 7;
    const int l    = lblk * 4 + w;    // this wave's output row

    const float SC = 2.885390081777927f;  // 2*log2(e): tanh(x)=1-2*rcp(exp2(SC*x)+1)

    // q row pre-scaled by SC, wave-uniform in registers.
    float4 qs[EE / 4];
    const float4* qrow = (const float4*)(q + (((size_t)b * LL + l) * HH + h) * EE);
    #pragma unroll
    for (int i = 0; i < EE / 4; i++) {
        float4 t = qrow[i];
        qs[i] = make_float4(SC * t.x, SC * t.y, SC * t.z, SC * t.w);
    }
    // v2 = -2*v, vsum = sum(v):  score = vsum + sum_e v2[e]*rcp(exp2(..)+1)
    float4 v2[EE / 4];
    float vsum = 0.f;
    const float4* vr = (const float4*)vvec;
    #pragma unroll
    for (int i = 0; i < EE / 4; i++) {
        float4 t = vr[i];
        vsum += t.x + t.y + t.z + t.w;
        v2[i] = make_float4(-2.f * t.x, -2.f * t.y, -2.f * t.z, -2.f * t.w);
    }

    // ---- Phase 1: scores. Lane owns s = lane + i*64, i = 0..7. ----
    float sc[SS / 64];
    const float4* krow = (const float4*)(k + ((size_t)b * SS * HH + h) * EE);
    for (int t = 0; t < SS / TS; t++) {
        __syncthreads();
        #pragma unroll
        for (int i = 0; i < (TS * (EE / 4)) / 256; i++) {
            int idx = tid + i * 256;
            int ss  = idx >> 3;       // 0..127
            int e4  = idx & 7;        // consecutive threads -> coalesced
            float4 kv = krow[(size_t)(t * TS + ss) * (HH * EE / 4) + e4];
            kv.x *= SC; kv.y *= SC; kv.z *= SC; kv.w *= SC;
            sk[e4][ss ^ e4] = kv;     // swizzled store
        }
        __syncthreads();
        #pragma unroll
        for (int j = 0; j < 2; j++) {
            int ssl = lane + j * 64;
            float acc = 0.f;
            #pragma unroll
            for (int e4 = 0; e4 < EE / 4; e4++) {
                float4 kv = sk[e4][ssl ^ e4];   // conflict-free ds_read_b128
                float4 qv = qs[e4];
                float4 vv = v2[e4];
                acc += vv.x * __builtin_amdgcn_rcpf(fast_exp2(qv.x + kv.x) + 1.f);
                acc += vv.y * __builtin_amdgcn_rcpf(fast_exp2(qv.y + kv.y) + 1.f);
                acc += vv.z * __builtin_amdgcn_rcpf(fast_exp2(qv.z + kv.z) + 1.f);
                acc += vv.w * __builtin_amdgcn_rcpf(fast_exp2(qv.w + kv.w) + 1.f);
            }
            sc[t * 2 + j] = vsum + acc;
        }
    }

    // ---- Phase 2: masks + per-wave softmax, probs -> LDS as bf16. ----
    const float* mrow = mask + (size_t)l * SS;
    const float* kl   = klen + (size_t)b * SS;
    #pragma unroll
    for (int i = 0; i < SS / 64; i++) {
        int s = lane + i * 64;
        sc[i] += mrow[s] + kl[s];
    }
    float m = sc[0];
    #pragma unroll
    for (int i = 1; i < SS / 64; i++) m = fmaxf(m, sc[i]);
    #pragma unroll
    for (int off = 1; off < 64; off <<= 1) m = fmaxf(m, __shfl_xor(m, off, 64));
    float p[SS / 64];
    float ssum = 0.f;
    #pragma unroll
    for (int i = 0; i < SS / 64; i++) {
        p[i] = __expf(sc[i] - m);
        ssum += p[i];
    }
    #pragma unroll
    for (int off = 1; off < 64; off <<= 1) ssum += __shfl_xor(ssum, off, 64);
    float inv = __builtin_amdgcn_rcpf(ssum);
    #pragma unroll
    for (int i = 0; i < SS / 64; i++) sAb[w][lane + i * 64] = f2bf(p[i] * inv);

    __syncthreads();   // all 4 waves read all 4 rows of sAb below

    // ---- Phase 3: PV via MFMA. (4x512)x(512x64), one 16-wide d-chunk/wave.
    // A-frag: A[m=lane&15][kk=quad*8+j], rows m>=4 are zero.
    // B-frag: B[kk=quad*8+j][n=lane&15] = V[s=kk][d=w*16+n], from L2.
    const int am  = lane & 15;        // A row / B column-within-chunk
    const int qd  = lane >> 4;        // quad
    const int dof = w * 16 + am;      // this lane's d
    const float* vbase = vals + (((size_t)b * SS * HH + h) * DD) + dof;
    f32x4 acc = {0.f, 0.f, 0.f, 0.f};
    for (int c = 0; c < SS / 32; c++) {           // 16 k-chunks of 32
        int s0 = c * 32 + qd * 8;
        bf16x8 af = {0, 0, 0, 0, 0, 0, 0, 0};
        if (am < 4) af = *(const bf16x8*)&sAb[am][c * 32 + qd * 8];
        bf16x8 bfv;
        #pragma unroll
        for (int j = 0; j < 8; j++) {
            bfv[j] = f2bf(vbase[(size_t)(s0 + j) * (HH * DD)]);
        }
        acc = __builtin_amdgcn_mfma_f32_16x16x32_bf16(af, bfv, acc, 0, 0, 0);
    }
    // C layout: col = lane&15 (d within chunk), row = qd*4 + reg.
    // Valid rows 0..3 live entirely in quad 0.
    if (qd == 0) {
        float* orow = out + ((((size_t)b * LL + lblk * 4) * HH + h) * DD) + dof;
        #pragma unroll
        for (int r = 0; r < 4; r++) {
            orow[(size_t)r * (HH * DD)] = acc[r];
        }
    }
}

extern "C" void kernel_launch(void* const* d_in, const int* in_sizes, int n_in,
                              void* d_out, int out_size, void* d_ws, size_t ws_size,
                              hipStream_t stream) {
    const float* q    = (const float*)d_in[0];  // (B,L,H,E)
    const float* k    = (const float*)d_in[1];  // (B,S,H,E)
    const float* vals = (const float*)d_in[2];  // (B,S,H,D)
    const float* vvec = (const float*)d_in[3];  // (E)
    const float* mask = (const float*)d_in[4];  // (L,S)
    const float* klen = (const float*)d_in[5];  // (B,S)
    float* outp = (float*)d_out;                // (B,L,H,D)

    dim3 grid(BB * HH * (LL / 4));   // one wave per (b,h,l) row
    dim3 block(256);
    addattn_kernel<<<grid, block, 0, stream>>>(q, k, vals, vvec, mask, klen, outp);
}